// Round 5
// baseline (825.354 us; speedup 1.0000x reference)
//
#include <hip/hip_runtime.h>
#include <math.h>

#define H_ 56
#define W_ 56
#define CIN 256
#define COUT 256
#define NB 8
#define SPIX 3136
#define KG 2304
#define MTOT 25088

typedef __bf16 v8bf __attribute__((ext_vector_type(8)));
typedef float  v4f  __attribute__((ext_vector_type(4)));

// ---------- pre-kernel 1: NCHW fp32 -> NHWC bf16
__global__ __launch_bounds__(256) void prep_x(const float* __restrict__ x,
                                              __bf16* __restrict__ xb) {
    __shared__ float tile[64][65];
    const int n = blockIdx.z, c0 = blockIdx.y * 64, s0 = blockIdx.x * 64;
    const int tid = threadIdx.x;
    const float* xp = x + (size_t)n * CIN * SPIX;
    __bf16* xo = xb + (size_t)n * SPIX * CIN;
#pragma unroll
    for (int i = 0; i < 16; ++i) {
        int idx = tid + i * 256;
        int cr = idx >> 6, sc = idx & 63;
        tile[cr][sc] = xp[(c0 + cr) * SPIX + s0 + sc];
    }
    __syncthreads();
#pragma unroll
    for (int i = 0; i < 16; ++i) {
        int idx = tid + i * 256;
        int sr = idx >> 6, cc = idx & 63;
        xo[(s0 + sr) * CIN + c0 + cc] = (__bf16)tile[cc][sr];
    }
}

// ---------- pre-kernel 2: weight (Cout,Cin,3,3) fp32 -> Bp[o][tap*256+c] bf16
__global__ __launch_bounds__(256) void prep_w(const float* __restrict__ w,
                                              __bf16* __restrict__ bp) {
    const int i = blockIdx.x * 256 + threadIdx.x;
    if (i < COUT * KG) {
        const int o = i / KG;
        const int rem = i - o * KG;
        const int c = rem / 9;
        const int tap = rem - c * 9;
        bp[(size_t)o * KG + tap * 256 + c] = (__bf16)w[i];
    }
}

// ---------- main: barrier-free fused deformable producer + bf16 MFMA, split-K x3
// 256 thr = 4 waves (wm = wave&1 m-half, wn = wave>>1 n-half); block tile
// 128(pixels) x 128(couts); wave tile 64x64. Each lane builds its A-frags
// DIRECTLY in MFMA A-layout (lane(l15,q): pixel mt*16+l15, chans q*8..+7)
// from 4 corner gathers -- no LDS, no __syncthreads in the K-loop.
__global__ __launch_bounds__(256, 3) void mdcn_wave(
    const __bf16* __restrict__ xb,     // NHWC bf16
    const float*  __restrict__ offs,   // (N,18,56,56)
    const float*  __restrict__ msk,    // (N,9,56,56)
    const __bf16* __restrict__ bp,     // Bp[o][tap*256+c]
    const float*  __restrict__ bias,
    float*        __restrict__ out)    // (N,256,56,56), pre-zeroed; atomic accum
{
    __shared__ __align__(16) float epi_s[4 * 64 * 20];   // epilogue only (20480 B)

    const int tid  = threadIdx.x;
    const int lane = tid & 63, wv = tid >> 6;
    const int wm = wv & 1, wn = wv >> 1;
    const int m0 = blockIdx.x * 128, o0 = blockIdx.y * 128;
    const int kz = blockIdx.z;                  // taps [3*kz, 3*kz+3)
    const int l15 = lane & 15, q = lane >> 4;

    v4f acc[4][4];
#pragma unroll
    for (int i = 0; i < 4; ++i)
#pragma unroll
        for (int j = 0; j < 4; ++j) acc[i][j] = (v4f)0.f;

#pragma unroll 1
    for (int tap = kz * 3; tap < kz * 3 + 3; ++tap) {
        const int kY = tap / 3, kX = tap - kY * 3;

        // ---- per-lane bilinear params for this lane's 4 pixels (mt*16+l15)
        int   gof[4][4];     // element offsets into xb (incl. +q*8)
        float cw [4][4];
#pragma unroll
        for (int mt = 0; mt < 4; ++mt) {
            const int pg = m0 + wm * 64 + mt * 16 + l15;
            const int n  = pg / SPIX;
            const int s  = pg - n * SPIX;
            const int h  = s / W_;
            const int w  = s - h * W_;
            const float dy = offs[n * (18 * SPIX) + (2 * tap) * SPIX + s];
            const float dx = offs[n * (18 * SPIX) + (2 * tap + 1) * SPIX + s];
            const float mk = msk[n * (9 * SPIX) + tap * SPIX + s];
            const float py = dy + (float)(kY + h - 1);   // PAD=1,STRIDE=1,DIL=1
            const float px = dx + (float)(kX + w - 1);
            const float fy0 = floorf(py), fx0 = floorf(px);
            const int y0 = (int)fy0, x0 = (int)fx0;
            const float wy1 = py - fy0, wx1 = px - fx0;
            const float wy0 = 1.0f - wy1, wx0 = 1.0f - wx1;
#pragma unroll
            for (int t = 0; t < 4; ++t) {
                const int yi = y0 + (t >> 1), xi = x0 + (t & 1);
                const bool valid = (yi >= 0) & (yi < H_) & (xi >= 0) & (xi < W_);
                const int yc = min(max(yi, 0), H_ - 1);
                const int xc = min(max(xi, 0), W_ - 1);
                gof[mt][t] = ((n * SPIX + yc * W_ + xc) << 8) + q * 8;
                cw [mt][t] = valid
                    ? (((t >> 1) ? wy1 : wy0) * ((t & 1) ? wx1 : wx0) * mk) : 0.0f;
            }
        }

        // ---- B row bases for this tap (frag row o, k-offset tap*256 + q*8)
        int bb[4];
#pragma unroll
        for (int nt = 0; nt < 4; ++nt)
            bb[nt] = (o0 + wn * 64 + nt * 16 + l15) * KG + tap * 256 + q * 8;

        // ---- barrier-free K-loop: 8 chan-chunks of 32 (imm-offset loads)
#pragma unroll
        for (int c8 = 0; c8 < 8; ++c8) {
            v8bf afr[4];
#pragma unroll
            for (int mt = 0; mt < 4; ++mt) {
                const v8bf g0 = *(const v8bf*)(xb + gof[mt][0] + c8 * 32);
                const v8bf g1 = *(const v8bf*)(xb + gof[mt][1] + c8 * 32);
                const v8bf g2 = *(const v8bf*)(xb + gof[mt][2] + c8 * 32);
                const v8bf g3 = *(const v8bf*)(xb + gof[mt][3] + c8 * 32);
                const float w0 = cw[mt][0], w1 = cw[mt][1];
                const float w2 = cw[mt][2], w3 = cw[mt][3];
                v8bf r;
#pragma unroll
                for (int j = 0; j < 8; ++j)
                    r[j] = (__bf16)(w0 * (float)g0[j] + w1 * (float)g1[j]
                                  + w2 * (float)g2[j] + w3 * (float)g3[j]);
                afr[mt] = r;
            }
            v8bf bfr[4];
#pragma unroll
            for (int nt = 0; nt < 4; ++nt)
                bfr[nt] = *(const v8bf*)(bp + bb[nt] + c8 * 32);
#pragma unroll
            for (int mt = 0; mt < 4; ++mt)
#pragma unroll
                for (int nt = 0; nt < 4; ++nt)
                    acc[mt][nt] = __builtin_amdgcn_mfma_f32_16x16x32_bf16(
                        afr[mt], bfr[nt], acc[mt][nt], 0, 0, 0);
        }
    }

    // ---- epilogue (R4-verified): per-wave 64x64 LDS transpose + fp32 atomicAdd
    float* epi = epi_s + wv * (64 * 20);
    const int pg = m0 + wm * 64 + lane;        // 64-span never crosses an image
    const int n_img = pg / SPIX;
    const int s_pix = pg - n_img * SPIX;
    float* outb = out + (size_t)n_img * COUT * SPIX + s_pix;

#pragma unroll
    for (int nt = 0; nt < 4; ++nt) {
        const float bv = (kz == 0) ? bias[o0 + wn * 64 + nt * 16 + l15] : 0.0f;
#pragma unroll
        for (int mt = 0; mt < 4; ++mt)
#pragma unroll
            for (int r = 0; r < 4; ++r)
                epi[(mt * 16 + q * 4 + r) * 20 + l15] = acc[mt][nt][r] + bv;
        __syncthreads();
#pragma unroll
        for (int c4 = 0; c4 < 4; ++c4) {
            v4f vv = *(const v4f*)(epi + lane * 20 + c4 * 4);
            const int ob = o0 + wn * 64 + nt * 16 + c4 * 4;
            atomicAdd(&outb[(size_t)(ob + 0) * SPIX], vv.x);
            atomicAdd(&outb[(size_t)(ob + 1) * SPIX], vv.y);
            atomicAdd(&outb[(size_t)(ob + 2) * SPIX], vv.z);
            atomicAdd(&outb[(size_t)(ob + 3) * SPIX], vv.w);
        }
        __syncthreads();
    }
}

// ---------- fallback (round-1 verified fp32 path, no workspace needed)
#define BM 64
#define BN 64
#define BKF 32
#define AST 68
#define BST 68
#define CST 65
__global__ __launch_bounds__(256) void mdcn_fallback(
    const float* __restrict__ xs, const float* __restrict__ offs,
    const float* __restrict__ msk, const float* __restrict__ wraw,
    const float* __restrict__ bias, float* __restrict__ out)
{
    __shared__ float smem[BKF * AST + BKF * BST];
    __shared__ int   sBase[4][BM];
    __shared__ float sWgt[4][BM];
    float (*At)[AST] = (float (*)[AST])smem;
    float (*Bt)[BST] = (float (*)[BST])(smem + BKF * AST);
    float (*Cs)[CST] = (float (*)[CST])smem;
    const int tid = threadIdx.x;
    const int m0 = blockIdx.x * BM;
    const int o0 = blockIdx.y * BN;
    const int n  = m0 / SPIX;
    const int s0 = m0 - n * SPIX;
    const int tx = tid & 15, ty = tid >> 4;
    float acc[4][4] = {};
    for (int k = 0; k < 9; ++k) {
        if (tid < BM) {
            const int s = s0 + tid;
            const int h = s / W_;
            const int w = s - h * W_;
            const int kY = k / 3, kX = k - kY * 3;
            const float dy = offs[(size_t)n * (18 * SPIX) + (size_t)(2 * k) * SPIX + s];
            const float dx = offs[(size_t)n * (18 * SPIX) + (size_t)(2 * k + 1) * SPIX + s];
            const float mk = msk[(size_t)n * (9 * SPIX) + (size_t)k * SPIX + s];
            const float py = dy + (float)(kY + h - 1);
            const float px = dx + (float)(kX + w - 1);
            const float fy0 = floorf(py), fx0 = floorf(px);
            const int y0 = (int)fy0, x0 = (int)fx0;
            const float wy1 = py - fy0, wx1 = px - fx0;
            const float wy0 = 1.0f - wy1, wx0 = 1.0f - wx1;
#pragma unroll
            for (int t = 0; t < 4; ++t) {
                const int yi = y0 + (t >> 1), xi = x0 + (t & 1);
                const bool valid = (yi >= 0) & (yi < H_) & (xi >= 0) & (xi < W_);
                const int yc = min(max(yi, 0), H_ - 1);
                const int xc = min(max(xi, 0), W_ - 1);
                float wt = ((t >> 1) ? wy1 : wy0) * ((t & 1) ? wx1 : wx0) * mk;
                sBase[t][tid] = n * (CIN * SPIX) + yc * W_ + xc;
                sWgt[t][tid] = valid ? wt : 0.0f;
            }
        }
        __syncthreads();
        for (int c0 = 0; c0 < CIN; c0 += BKF) {
#pragma unroll
            for (int i = 0; i < 8; ++i) {
                int idx = tid + i * 256;
                int row = idx >> 5, cc = idx & 31;
                int ce = (c0 + cc) * SPIX;
                At[cc][row] = sWgt[0][row] * xs[sBase[0][row] + ce]
                            + sWgt[1][row] * xs[sBase[1][row] + ce]
                            + sWgt[2][row] * xs[sBase[2][row] + ce]
                            + sWgt[3][row] * xs[sBase[3][row] + ce];
            }
#pragma unroll
            for (int i = 0; i < 8; ++i) {
                int idx = tid + i * 256;
                int kf = idx >> 6, o = idx & 63;
                Bt[kf][o] = wraw[(size_t)(o0 + o) * KG + (c0 + kf) * 9 + k];
            }
            __syncthreads();
#pragma unroll
            for (int kf = 0; kf < BKF; ++kf) {
                const float4 a = *(const float4*)&At[kf][ty * 4];
                const float4 b = *(const float4*)&Bt[kf][tx * 4];
                acc[0][0] = fmaf(a.x, b.x, acc[0][0]); acc[0][1] = fmaf(a.x, b.y, acc[0][1]);
                acc[0][2] = fmaf(a.x, b.z, acc[0][2]); acc[0][3] = fmaf(a.x, b.w, acc[0][3]);
                acc[1][0] = fmaf(a.y, b.x, acc[1][0]); acc[1][1] = fmaf(a.y, b.y, acc[1][1]);
                acc[1][2] = fmaf(a.y, b.z, acc[1][2]); acc[1][3] = fmaf(a.y, b.w, acc[1][3]);
                acc[2][0] = fmaf(a.z, b.x, acc[2][0]); acc[2][1] = fmaf(a.z, b.y, acc[2][1]);
                acc[2][2] = fmaf(a.z, b.z, acc[2][2]); acc[2][3] = fmaf(a.z, b.w, acc[2][3]);
                acc[3][0] = fmaf(a.w, b.x, acc[3][0]); acc[3][1] = fmaf(a.w, b.y, acc[3][1]);
                acc[3][2] = fmaf(a.w, b.z, acc[3][2]); acc[3][3] = fmaf(a.w, b.w, acc[3][3]);
            }
            __syncthreads();
        }
    }
#pragma unroll
    for (int i = 0; i < 4; ++i)
#pragma unroll
        for (int j = 0; j < 4; ++j)
            Cs[ty * 4 + i][tx * 4 + j] = acc[i][j] + bias[o0 + tx * 4 + j];
    __syncthreads();
    const int pix = tid & 63, ob = tid >> 6;
    float* outp = out + (size_t)n * COUT * SPIX + s0 + pix;
#pragma unroll
    for (int r = 0; r < 16; ++r) {
        int o = r * 4 + ob;
        outp[(size_t)(o0 + o) * SPIX] = Cs[pix][o];
    }
}

extern "C" void kernel_launch(void* const* d_in, const int* in_sizes, int n_in,
                              void* d_out, int out_size, void* d_ws, size_t ws_size,
                              hipStream_t stream) {
    const float* x    = (const float*)d_in[0];
    const float* offs = (const float*)d_in[1];
    const float* msk  = (const float*)d_in[2];
    const float* w    = (const float*)d_in[3];
    const float* bias = (const float*)d_in[4];
    float* out = (float*)d_out;

    const size_t xb_bytes = (size_t)NB * SPIX * CIN * sizeof(__bf16);   // 12.85 MB
    const size_t bp_bytes = (size_t)KG * COUT * sizeof(__bf16);         // 1.18 MB

    if (ws_size >= xb_bytes + bp_bytes) {
        __bf16* xb = (__bf16*)d_ws;
        __bf16* bp = (__bf16*)((char*)d_ws + xb_bytes);
        prep_x<<<dim3(49, 4, 8), 256, 0, stream>>>(x, xb);
        prep_w<<<dim3((COUT * KG + 255) / 256), 256, 0, stream>>>(w, bp);
        hipMemsetAsync(out, 0, (size_t)out_size * sizeof(float), stream);
        mdcn_wave<<<dim3(MTOT / 128, COUT / 128, 3), 256, 0, stream>>>(
            xb, offs, msk, bp, bias, out);
    } else {
        mdcn_fallback<<<dim3(MTOT / BM, COUT / BN), 256, 0, stream>>>(
            x, offs, msk, w, bias, out);
    }
}

// Round 6
// 298.794 us; speedup vs baseline: 2.7623x; 2.7623x over previous
//
#include <hip/hip_runtime.h>
#include <math.h>

#define H_ 56
#define W_ 56
#define CIN 256
#define COUT 256
#define NB 8
#define SPIX 3136
#define KG 2304
#define MTOT 25088

typedef __bf16 v8bf __attribute__((ext_vector_type(8)));
typedef float  v4f  __attribute__((ext_vector_type(4)));

__device__ __forceinline__ void async_copy16(const void* g, void* l) {
    __builtin_amdgcn_global_load_lds(
        (const __attribute__((address_space(1))) void*)g,
        (__attribute__((address_space(3))) void*)l, 16, 0, 0);
}

// ---------- pre-kernel 1: NCHW fp32 -> NHWC bf16
__global__ __launch_bounds__(256) void prep_x(const float* __restrict__ x,
                                              __bf16* __restrict__ xb) {
    __shared__ float tile[64][65];
    const int n = blockIdx.z, c0 = blockIdx.y * 64, s0 = blockIdx.x * 64;
    const int tid = threadIdx.x;
    const float* xp = x + (size_t)n * CIN * SPIX;
    __bf16* xo = xb + (size_t)n * SPIX * CIN;
#pragma unroll
    for (int i = 0; i < 16; ++i) {
        int idx = tid + i * 256;
        int cr = idx >> 6, sc = idx & 63;
        tile[cr][sc] = xp[(c0 + cr) * SPIX + s0 + sc];
    }
    __syncthreads();
#pragma unroll
    for (int i = 0; i < 16; ++i) {
        int idx = tid + i * 256;
        int sr = idx >> 6, cc = idx & 63;
        xo[(s0 + sr) * CIN + c0 + cc] = (__bf16)tile[cc][sr];
    }
}

// ---------- pre-kernel 2: weight (Cout,Cin,3,3) fp32 -> Bp[o][tap*256+c] bf16
__global__ __launch_bounds__(256) void prep_w(const float* __restrict__ w,
                                              __bf16* __restrict__ bp) {
    const int i = blockIdx.x * 256 + threadIdx.x;
    if (i < COUT * KG) {
        const int o = i / KG;
        const int rem = i - o * KG;
        const int c = rem / 9;
        const int tap = rem - c * 9;
        bp[(size_t)o * KG + tap * 256 + c] = (__bf16)w[i];
    }
}

// ---------- phase 1: deformable im2col -> V[pix][tap*256+c] bf16
// 32 pixels/block; thread = (pixel, 32-chan group). 8 threads per pixel make
// each corner read a contiguous 512B burst; each (pixel,tap) gathered once.
__global__ __launch_bounds__(256) void im2col_v(
    const __bf16* __restrict__ xb,     // NHWC bf16
    const float*  __restrict__ offs,   // (N,18,56,56)
    const float*  __restrict__ msk,    // (N,9,56,56)
    __bf16*       __restrict__ V)      // [MTOT][KG]
{
    __shared__ int   sB[9 * 32 * 4];
    __shared__ float sW[9 * 32 * 4];
    const int tid = threadIdx.x;

    // phase A: all 9 taps' bilinear params for the block's 32 pixels
    for (int idx = tid; idx < 288; idx += 256) {
        const int tap = idx >> 5, pl = idx & 31;
        const int pg = blockIdx.x * 32 + pl;       // 3136%32==0: single image
        const int n  = pg / SPIX;
        const int s  = pg - n * SPIX;
        const int h  = s / W_;
        const int w  = s - h * W_;
        const int kY = tap / 3, kX = tap - kY * 3;
        const float dy = offs[n * (18 * SPIX) + (2 * tap) * SPIX + s];
        const float dx = offs[n * (18 * SPIX) + (2 * tap + 1) * SPIX + s];
        const float mk = msk[n * (9 * SPIX) + tap * SPIX + s];
        const float py = dy + (float)(kY + h - 1);  // PAD=1,STRIDE=1,DIL=1
        const float px = dx + (float)(kX + w - 1);
        const float fy0 = floorf(py), fx0 = floorf(px);
        const int y0 = (int)fy0, x0 = (int)fx0;
        const float wy1 = py - fy0, wx1 = px - fx0;
        const float wy0 = 1.0f - wy1, wx0 = 1.0f - wx1;
#pragma unroll
        for (int t = 0; t < 4; ++t) {
            const int yi = y0 + (t >> 1), xi = x0 + (t & 1);
            const bool valid = (yi >= 0) & (yi < H_) & (xi >= 0) & (xi < W_);
            const int yc = min(max(yi, 0), H_ - 1);
            const int xc = min(max(xi, 0), W_ - 1);
            sB[(tap * 32 + pl) * 4 + t] = (n * SPIX + yc * W_ + xc) * CIN;
            sW[(tap * 32 + pl) * 4 + t] = valid
                ? (((t >> 1) ? wy1 : wy0) * ((t & 1) ? wx1 : wx0) * mk) : 0.0f;
        }
    }
    __syncthreads();

    // phase B: gather + combine + store (barrier-free)
    const int pl = tid >> 3, cg = tid & 7;
    const int pg = blockIdx.x * 32 + pl;
    __bf16* vout = V + (size_t)pg * KG + cg * 32;

#pragma unroll 1
    for (int tap = 0; tap < 9; ++tap) {
        const int pbase = (tap * 32 + pl) * 4;
        const int b0 = sB[pbase + 0] + cg * 32, b1 = sB[pbase + 1] + cg * 32;
        const int b2 = sB[pbase + 2] + cg * 32, b3 = sB[pbase + 3] + cg * 32;
        const float w0 = sW[pbase + 0], w1 = sW[pbase + 1];
        const float w2 = sW[pbase + 2], w3 = sW[pbase + 3];
#pragma unroll
        for (int u = 0; u < 4; ++u) {
            const v8bf g0 = *(const v8bf*)(xb + b0 + u * 8);
            const v8bf g1 = *(const v8bf*)(xb + b1 + u * 8);
            const v8bf g2 = *(const v8bf*)(xb + b2 + u * 8);
            const v8bf g3 = *(const v8bf*)(xb + b3 + u * 8);
            v8bf r;
#pragma unroll
            for (int j = 0; j < 8; ++j)
                r[j] = (__bf16)(w0 * (float)g0[j] + w1 * (float)g1[j]
                              + w2 * (float)g2[j] + w3 * (float)g3[j]);
            *(v8bf*)(vout + tap * 256 + u * 8) = r;
        }
    }
}

// ---------- phase 2: dense bf16 MFMA GEMM  out[o][pix] = sum_k V[pix][k]*Bp[o][k]
// block: 512 thr = 8 waves; tile 64(m=pixels) x 256(n=full Cout); wave 32x64.
// BK=64; A+B staged via global_load_lds (16B), XOR-swizzled chunks (2-way=free).
__global__ __launch_bounds__(512, 4) void gemm_v(
    const __bf16* __restrict__ V,      // [MTOT][KG]
    const __bf16* __restrict__ bp,     // [COUT][KG]
    const float*  __restrict__ bias,
    float*        __restrict__ out)    // (N,256,56,56)
{
    __shared__ __align__(16) char smem[40960];     // A 8KB | B 32KB ; epi aliases
    __bf16* As = (__bf16*)smem;                    // [64][64]  (row=128B, 8 chunks)
    __bf16* Bs = (__bf16*)(smem + 8192);           // [256][64]

    const int tid  = threadIdx.x;
    const int lane = tid & 63, wv = tid >> 6;      // 8 waves
    const int wm = wv & 1, wn = wv >> 1;           // m-half 32, n-quarter 64
    const int m0 = blockIdx.x * 64;
    const int l15 = lane & 15, q = lane >> 4;

    v4f acc[2][4];
#pragma unroll
    for (int i = 0; i < 2; ++i)
#pragma unroll
        for (int j = 0; j < 4; ++j) acc[i][j] = (v4f)0.f;

    // per-lane staging identities (constant over K-loop)
    const int arow = (wv << 3) + (lane >> 3);                  // A row this lane loads
    const int alc  = (lane & 7) ^ (arow & 7);                  // logical chunk (swizzle)
    const __bf16* agp = V + (size_t)(m0 + arow) * KG + alc * 8;
    char* alds = smem + (wv << 10);

#pragma unroll 1
    for (int k0 = 0; k0 < KG; k0 += 64) {
        __syncthreads();                       // prev frags consumed
        async_copy16(agp + k0, alds);
#pragma unroll
        for (int t = 0; t < 4; ++t) {
            const int brow = t * 64 + (wv << 3) + (lane >> 3);
            const int blc  = (lane & 7) ^ (brow & 7);
            async_copy16(bp + (size_t)brow * KG + k0 + blc * 8,
                         smem + 8192 + ((t * 8 + wv) << 10));
        }
        __syncthreads();                       // tiles ready (vmcnt drained)

#pragma unroll
        for (int kf = 0; kf < 2; ++kf) {
            v8bf afr[2], bfr[4];
#pragma unroll
            for (int mt = 0; mt < 2; ++mt) {
                const int row = wm * 32 + mt * 16 + l15;
                const int pch = (kf * 4 + q) ^ (row & 7);
                afr[mt] = *(const v8bf*)(As + row * 64 + pch * 8);
            }
#pragma unroll
            for (int nt = 0; nt < 4; ++nt) {
                const int row = wn * 64 + nt * 16 + l15;
                const int pch = (kf * 4 + q) ^ (row & 7);
                bfr[nt] = *(const v8bf*)(Bs + row * 64 + pch * 8);
            }
#pragma unroll
            for (int mt = 0; mt < 2; ++mt)
#pragma unroll
                for (int nt = 0; nt < 4; ++nt)
                    acc[mt][nt] = __builtin_amdgcn_mfma_f32_16x16x32_bf16(
                        afr[mt], bfr[nt], acc[mt][nt], 0, 0, 0);
        }
    }

    __syncthreads();                           // all frag reads done; alias LDS
    // epilogue: per-wave 32x64 transpose (stride 17 fp32), coalesced NCHW stores
    float* epi = (float*)(smem + wv * 2176);   // 32*17*4 B, private per wave
    const int pixbase = m0 + wm * 32;          // 64|SPIX -> single image
    const int n_img = pixbase / SPIX;
    const int s_base = pixbase - n_img * SPIX;
    float* outb = out + (size_t)n_img * COUT * SPIX + s_base;

#pragma unroll
    for (int nt = 0; nt < 4; ++nt) {
        const float bv = bias[wn * 64 + nt * 16 + l15];
#pragma unroll
        for (int mt = 0; mt < 2; ++mt)
#pragma unroll
            for (int r = 0; r < 4; ++r)
                epi[(mt * 16 + q * 4 + r) * 17 + l15] = acc[mt][nt][r] + bv;
        __syncthreads();
        const int m = lane & 31, oh = lane >> 5;
#pragma unroll
        for (int oc = 0; oc < 8; ++oc) {
            const float v = epi[m * 17 + oc * 2 + oh];
            const int o = wn * 64 + nt * 16 + oc * 2 + oh;
            outb[(size_t)o * SPIX + m] = v;
        }
        __syncthreads();
    }
}

// ---------- R4-verified fused kernel (fallback when ws can't hold V)
__global__ __launch_bounds__(256, 3) void mdcn_fused(
    const __bf16* __restrict__ xb, const float* __restrict__ offs,
    const float* __restrict__ msk, const __bf16* __restrict__ bp,
    const float* __restrict__ bias, float* __restrict__ out)
{
    __shared__ __align__(16) char smem[24576];
    __bf16* A0 = (__bf16*)smem;
    __bf16* A1 = (__bf16*)(smem + 10240);
    int*    sBase = (int*)(smem + 20480);
    float*  sWgt  = (float*)(smem + 22528);
    const int tid  = threadIdx.x;
    const int lane = tid & 63, wv = tid >> 6;
    const int wm = wv & 1, wn = wv >> 1;
    const int m0 = blockIdx.x * 128, o0 = blockIdx.y * 128;
    const int kz = blockIdx.z;
    const int tap_lo = kz ? 5 : 0, tap_hi = kz ? 9 : 5;
    const int l15 = lane & 15, q = lane >> 4;
    const int prow = tid >> 2, pcg = tid & 3;
    v4f acc[4][4];
#pragma unroll
    for (int i = 0; i < 4; ++i)
#pragma unroll
        for (int j = 0; j < 4; ++j) acc[i][j] = (v4f)0.f;
    for (int tap = tap_lo; tap < tap_hi; ++tap) {
        if (tid < 128) {
            const int pg = m0 + tid;
            const int n  = pg / SPIX;
            const int s  = pg - n * SPIX;
            const int h  = s / W_;
            const int w  = s - h * W_;
            const int kY = tap / 3, kX = tap - kY * 3;
            const float dy = offs[n * (18 * SPIX) + (2 * tap) * SPIX + s];
            const float dx = offs[n * (18 * SPIX) + (2 * tap + 1) * SPIX + s];
            const float mk = msk[n * (9 * SPIX) + tap * SPIX + s];
            const float py = dy + (float)(kY + h - 1);
            const float px = dx + (float)(kX + w - 1);
            const float fy0 = floorf(py), fx0 = floorf(px);
            const int y0 = (int)fy0, x0 = (int)fx0;
            const float wy1 = py - fy0, wx1 = px - fx0;
            const float wy0 = 1.0f - wy1, wx0 = 1.0f - wx1;
#pragma unroll
            for (int t = 0; t < 4; ++t) {
                const int yi = y0 + (t >> 1), xi = x0 + (t & 1);
                const bool valid = (yi >= 0) & (yi < H_) & (xi >= 0) & (xi < W_);
                const int yc = min(max(yi, 0), H_ - 1);
                const int xc = min(max(xi, 0), W_ - 1);
                sBase[t * 128 + tid] = (n * SPIX + yc * W_ + xc) * CIN;
                sWgt [t * 128 + tid] = valid
                    ? (((t >> 1) ? wy1 : wy0) * ((t & 1) ? wx1 : wx0) * mk) : 0.0f;
            }
        }
        __syncthreads();
        int   cb0[4], cb1[4];
        float cw0[4], cw1[4];
#pragma unroll
        for (int t = 0; t < 4; ++t) {
            cb0[t] = sBase[t * 128 + prow];
            cw0[t] = sWgt [t * 128 + prow];
            cb1[t] = sBase[t * 128 + prow + 64];
            cw1[t] = sWgt [t * 128 + prow + 64];
        }
        v8bf rv[8];
        {
            const int cch = pcg * 8;
#pragma unroll
            for (int t = 0; t < 4; ++t) {
                rv[t]     = *(const v8bf*)(xb + cb0[t] + cch);
                rv[4 + t] = *(const v8bf*)(xb + cb1[t] + cch);
            }
        }
#pragma unroll
        for (int c8 = 0; c8 < 8; ++c8) {
            const int kk = tap * 8 + c8;
            __bf16* Ab = (kk & 1) ? A1 : A0;
            v8bf r0, r1;
#pragma unroll
            for (int j = 0; j < 8; ++j) {
                r0[j] = (__bf16)(cw0[0] * (float)rv[0][j] + cw0[1] * (float)rv[1][j]
                               + cw0[2] * (float)rv[2][j] + cw0[3] * (float)rv[3][j]);
                r1[j] = (__bf16)(cw1[0] * (float)rv[4][j] + cw1[1] * (float)rv[5][j]
                               + cw1[2] * (float)rv[6][j] + cw1[3] * (float)rv[7][j]);
            }
            *(v8bf*)(Ab + prow * 40 + pcg * 8) = r0;
            *(v8bf*)(Ab + (prow + 64) * 40 + pcg * 8) = r1;
            if (c8 < 7) {
                const int cch = (c8 + 1) * 32 + pcg * 8;
#pragma unroll
                for (int t = 0; t < 4; ++t) {
                    rv[t]     = *(const v8bf*)(xb + cb0[t] + cch);
                    rv[4 + t] = *(const v8bf*)(xb + cb1[t] + cch);
                }
            }
            v8bf bfr[4];
#pragma unroll
            for (int nt = 0; nt < 4; ++nt)
                bfr[nt] = *(const v8bf*)(bp
                    + (size_t)(o0 + wn * 64 + nt * 16 + l15) * KG + kk * 32 + q * 8);
            __syncthreads();
            v8bf afr[4];
#pragma unroll
            for (int mt = 0; mt < 4; ++mt)
                afr[mt] = *(const v8bf*)(Ab + (wm * 64 + mt * 16 + l15) * 40 + q * 8);
#pragma unroll
            for (int mt = 0; mt < 4; ++mt)
#pragma unroll
                for (int nt = 0; nt < 4; ++nt)
                    acc[mt][nt] = __builtin_amdgcn_mfma_f32_16x16x32_bf16(
                        afr[mt], bfr[nt], acc[mt][nt], 0, 0, 0);
        }
    }
    __syncthreads();
    float* epi = (float*)smem + wv * (64 * 20);
    const int pg = m0 + wm * 64 + lane;
    const int n_img = pg / SPIX;
    const int s_pix = pg - n_img * SPIX;
    float* outb = out + (size_t)n_img * COUT * SPIX + s_pix;
#pragma unroll
    for (int nt = 0; nt < 4; ++nt) {
        const float bv = (kz == 0) ? bias[o0 + wn * 64 + nt * 16 + l15] : 0.0f;
#pragma unroll
        for (int mt = 0; mt < 4; ++mt)
#pragma unroll
            for (int r = 0; r < 4; ++r)
                epi[(mt * 16 + q * 4 + r) * 20 + l15] = acc[mt][nt][r] + bv;
        __syncthreads();
#pragma unroll
        for (int c4 = 0; c4 < 4; ++c4) {
            v4f vv = *(const v4f*)(epi + lane * 20 + c4 * 4);
            const int ob = o0 + wn * 64 + nt * 16 + c4 * 4;
            atomicAdd(&outb[(size_t)(ob + 0) * SPIX], vv.x);
            atomicAdd(&outb[(size_t)(ob + 1) * SPIX], vv.y);
            atomicAdd(&outb[(size_t)(ob + 2) * SPIX], vv.z);
            atomicAdd(&outb[(size_t)(ob + 3) * SPIX], vv.w);
        }
        __syncthreads();
    }
}

// ---------- fp32 fallback (round-1 verified, no workspace)
#define BM 64
#define BN 64
#define BKF 32
#define AST 68
#define BST 68
#define CST 65
__global__ __launch_bounds__(256) void mdcn_fallback(
    const float* __restrict__ xs, const float* __restrict__ offs,
    const float* __restrict__ msk, const float* __restrict__ wraw,
    const float* __restrict__ bias, float* __restrict__ out)
{
    __shared__ float smem[BKF * AST + BKF * BST];
    __shared__ int   sBase[4][BM];
    __shared__ float sWgt[4][BM];
    float (*At)[AST] = (float (*)[AST])smem;
    float (*Bt)[BST] = (float (*)[BST])(smem + BKF * AST);
    float (*Cs)[CST] = (float (*)[CST])smem;
    const int tid = threadIdx.x;
    const int m0 = blockIdx.x * BM;
    const int o0 = blockIdx.y * BN;
    const int n  = m0 / SPIX;
    const int s0 = m0 - n * SPIX;
    const int tx = tid & 15, ty = tid >> 4;
    float acc[4][4] = {};
    for (int k = 0; k < 9; ++k) {
        if (tid < BM) {
            const int s = s0 + tid;
            const int h = s / W_;
            const int w = s - h * W_;
            const int kY = k / 3, kX = k - kY * 3;
            const float dy = offs[(size_t)n * (18 * SPIX) + (size_t)(2 * k) * SPIX + s];
            const float dx = offs[(size_t)n * (18 * SPIX) + (size_t)(2 * k + 1) * SPIX + s];
            const float mk = msk[(size_t)n * (9 * SPIX) + (size_t)k * SPIX + s];
            const float py = dy + (float)(kY + h - 1);
            const float px = dx + (float)(kX + w - 1);
            const float fy0 = floorf(py), fx0 = floorf(px);
            const int y0 = (int)fy0, x0 = (int)fx0;
            const float wy1 = py - fy0, wx1 = px - fx0;
            const float wy0 = 1.0f - wy1, wx0 = 1.0f - wx1;
#pragma unroll
            for (int t = 0; t < 4; ++t) {
                const int yi = y0 + (t >> 1), xi = x0 + (t & 1);
                const bool valid = (yi >= 0) & (yi < H_) & (xi >= 0) & (xi < W_);
                const int yc = min(max(yi, 0), H_ - 1);
                const int xc = min(max(xi, 0), W_ - 1);
                float wt = ((t >> 1) ? wy1 : wy0) * ((t & 1) ? wx1 : wx0) * mk;
                sBase[t][tid] = n * (CIN * SPIX) + yc * W_ + xc;
                sWgt[t][tid] = valid ? wt : 0.0f;
            }
        }
        __syncthreads();
        for (int c0 = 0; c0 < CIN; c0 += BKF) {
#pragma unroll
            for (int i = 0; i < 8; ++i) {
                int idx = tid + i * 256;
                int row = idx >> 5, cc = idx & 31;
                int ce = (c0 + cc) * SPIX;
                At[cc][row] = sWgt[0][row] * xs[sBase[0][row] + ce]
                            + sWgt[1][row] * xs[sBase[1][row] + ce]
                            + sWgt[2][row] * xs[sBase[2][row] + ce]
                            + sWgt[3][row] * xs[sBase[3][row] + ce];
            }
#pragma unroll
            for (int i = 0; i < 8; ++i) {
                int idx = tid + i * 256;
                int kf = idx >> 6, o = idx & 63;
                Bt[kf][o] = wraw[(size_t)(o0 + o) * KG + (c0 + kf) * 9 + k];
            }
            __syncthreads();
#pragma unroll
            for (int kf = 0; kf < BKF; ++kf) {
                const float4 a = *(const float4*)&At[kf][ty * 4];
                const float4 b = *(const float4*)&Bt[kf][tx * 4];
                acc[0][0] = fmaf(a.x, b.x, acc[0][0]); acc[0][1] = fmaf(a.x, b.y, acc[0][1]);
                acc[0][2] = fmaf(a.x, b.z, acc[0][2]); acc[0][3] = fmaf(a.x, b.w, acc[0][3]);
                acc[1][0] = fmaf(a.y, b.x, acc[1][0]); acc[1][1] = fmaf(a.y, b.y, acc[1][1]);
                acc[1][2] = fmaf(a.y, b.z, acc[1][2]); acc[1][3] = fmaf(a.y, b.w, acc[1][3]);
                acc[2][0] = fmaf(a.z, b.x, acc[2][0]); acc[2][1] = fmaf(a.z, b.y, acc[2][1]);
                acc[2][2] = fmaf(a.z, b.z, acc[2][2]); acc[2][3] = fmaf(a.z, b.w, acc[2][3]);
                acc[3][0] = fmaf(a.w, b.x, acc[3][0]); acc[3][1] = fmaf(a.w, b.y, acc[3][1]);
                acc[3][2] = fmaf(a.w, b.z, acc[3][2]); acc[3][3] = fmaf(a.w, b.w, acc[3][3]);
            }
            __syncthreads();
        }
    }
#pragma unroll
    for (int i = 0; i < 4; ++i)
#pragma unroll
        for (int j = 0; j < 4; ++j)
            Cs[ty * 4 + i][tx * 4 + j] = acc[i][j] + bias[o0 + tx * 4 + j];
    __syncthreads();
    const int pix = tid & 63, ob = tid >> 6;
    float* outp = out + (size_t)n * COUT * SPIX + s0 + pix;
#pragma unroll
    for (int r = 0; r < 16; ++r) {
        int o = r * 4 + ob;
        outp[(size_t)(o0 + o) * SPIX] = Cs[pix][o];
    }
}

extern "C" void kernel_launch(void* const* d_in, const int* in_sizes, int n_in,
                              void* d_out, int out_size, void* d_ws, size_t ws_size,
                              hipStream_t stream) {
    const float* x    = (const float*)d_in[0];
    const float* offs = (const float*)d_in[1];
    const float* msk  = (const float*)d_in[2];
    const float* w    = (const float*)d_in[3];
    const float* bias = (const float*)d_in[4];
    float* out = (float*)d_out;

    const size_t xb_bytes = (size_t)NB * SPIX * CIN * sizeof(__bf16);    // 12.85 MB
    const size_t bp_bytes = (size_t)KG * COUT * sizeof(__bf16);          // 1.18 MB
    const size_t v_bytes  = (size_t)MTOT * KG * sizeof(__bf16);          // 115.6 MB

    if (ws_size >= xb_bytes + bp_bytes + v_bytes) {
        __bf16* xb = (__bf16*)d_ws;
        __bf16* bp = (__bf16*)((char*)d_ws + xb_bytes);
        __bf16* V  = (__bf16*)((char*)d_ws + xb_bytes + bp_bytes);
        prep_x<<<dim3(49, 4, 8), 256, 0, stream>>>(x, xb);
        prep_w<<<dim3((COUT * KG + 255) / 256), 256, 0, stream>>>(w, bp);
        im2col_v<<<dim3(MTOT / 32), 256, 0, stream>>>(xb, offs, msk, V);
        gemm_v<<<dim3(MTOT / 64), 512, 0, stream>>>(V, bp, bias, out);
    } else if (ws_size >= xb_bytes + bp_bytes) {
        __bf16* xb = (__bf16*)d_ws;
        __bf16* bp = (__bf16*)((char*)d_ws + xb_bytes);
        prep_x<<<dim3(49, 4, 8), 256, 0, stream>>>(x, xb);
        prep_w<<<dim3((COUT * KG + 255) / 256), 256, 0, stream>>>(w, bp);
        hipMemsetAsync(out, 0, (size_t)out_size * sizeof(float), stream);
        mdcn_fused<<<dim3(MTOT / 128, COUT / 128, 2), 256, 0, stream>>>(
            xb, offs, msk, bp, bias, out);
    } else {
        mdcn_fallback<<<dim3(MTOT / BM, COUT / BN), 256, 0, stream>>>(
            x, offs, msk, w, bias, out);
    }
}

// Round 7
// 188.296 us; speedup vs baseline: 4.3833x; 1.5868x over previous
//
#include <hip/hip_runtime.h>
#include <math.h>

#define H_ 56
#define W_ 56
#define CIN 256
#define COUT 256
#define NB 8
#define SPIX 3136
#define KG 2304
#define MTOT 25088

typedef __bf16 v8bf __attribute__((ext_vector_type(8)));
typedef float  v4f  __attribute__((ext_vector_type(4)));

__device__ __forceinline__ void async_copy16(const void* g, void* l) {
    __builtin_amdgcn_global_load_lds(
        (const __attribute__((address_space(1))) void*)g,
        (__attribute__((address_space(3))) void*)l, 16, 0, 0);
}

// ---------- pre-kernel 1: NCHW fp32 -> NHWC bf16
__global__ __launch_bounds__(256) void prep_x(const float* __restrict__ x,
                                              __bf16* __restrict__ xb) {
    __shared__ float tile[64][65];
    const int n = blockIdx.z, c0 = blockIdx.y * 64, s0 = blockIdx.x * 64;
    const int tid = threadIdx.x;
    const float* xp = x + (size_t)n * CIN * SPIX;
    __bf16* xo = xb + (size_t)n * SPIX * CIN;
#pragma unroll
    for (int i = 0; i < 16; ++i) {
        int idx = tid + i * 256;
        int cr = idx >> 6, sc = idx & 63;
        tile[cr][sc] = xp[(c0 + cr) * SPIX + s0 + sc];
    }
    __syncthreads();
#pragma unroll
    for (int i = 0; i < 16; ++i) {
        int idx = tid + i * 256;
        int sr = idx >> 6, cc = idx & 63;
        xo[(s0 + sr) * CIN + c0 + cc] = (__bf16)tile[cc][sr];
    }
}

// ---------- pre-kernel 2: weight (Cout,Cin,3,3) fp32 -> Bp[o][tap*256+c] bf16
__global__ __launch_bounds__(256) void prep_w(const float* __restrict__ w,
                                              __bf16* __restrict__ bp) {
    const int i = blockIdx.x * 256 + threadIdx.x;
    if (i < COUT * KG) {
        const int o = i / KG;
        const int rem = i - o * KG;
        const int c = rem / 9;
        const int tap = rem - c * 9;
        bp[(size_t)o * KG + tap * 256 + c] = (__bf16)w[i];
    }
}

// ---------- phase 1: deformable im2col -> V[pix][tap*256+c] bf16
// 32 pixels x 3 taps per block (blockIdx.y = tap triple); thread = (pixel,
// 8-chan lane). chunk = u*64 + cg*8 -> every load & store instruction covers
// a full 128B line per 8-lane group (fixes R6's 2.1x write amplification).
__global__ __launch_bounds__(256) void im2col_v(
    const __bf16* __restrict__ xb,     // NHWC bf16
    const float*  __restrict__ offs,   // (N,18,56,56)
    const float*  __restrict__ msk,    // (N,9,56,56)
    __bf16*       __restrict__ V)      // [MTOT][KG]
{
    __shared__ int   sB[3 * 32 * 4];
    __shared__ float sW[3 * 32 * 4];
    const int tid = threadIdx.x;
    const int tapbase = blockIdx.y * 3;

    // phase A: bilinear params for this block's 32 pixels x 3 taps
    if (tid < 96) {
        const int tl = tid >> 5, pl = tid & 31;
        const int tap = tapbase + tl;
        const int pg = blockIdx.x * 32 + pl;       // 3136%32==0: single image
        const int n  = pg / SPIX;
        const int s  = pg - n * SPIX;
        const int h  = s / W_;
        const int w  = s - h * W_;
        const int kY = tap / 3, kX = tap - kY * 3;
        const float dy = offs[n * (18 * SPIX) + (2 * tap) * SPIX + s];
        const float dx = offs[n * (18 * SPIX) + (2 * tap + 1) * SPIX + s];
        const float mk = msk[n * (9 * SPIX) + tap * SPIX + s];
        const float py = dy + (float)(kY + h - 1);  // PAD=1,STRIDE=1,DIL=1
        const float px = dx + (float)(kX + w - 1);
        const float fy0 = floorf(py), fx0 = floorf(px);
        const int y0 = (int)fy0, x0 = (int)fx0;
        const float wy1 = py - fy0, wx1 = px - fx0;
        const float wy0 = 1.0f - wy1, wx0 = 1.0f - wx1;
#pragma unroll
        for (int t = 0; t < 4; ++t) {
            const int yi = y0 + (t >> 1), xi = x0 + (t & 1);
            const bool valid = (yi >= 0) & (yi < H_) & (xi >= 0) & (xi < W_);
            const int yc = min(max(yi, 0), H_ - 1);
            const int xc = min(max(xi, 0), W_ - 1);
            sB[(tl * 32 + pl) * 4 + t] = (n * SPIX + yc * W_ + xc) * CIN;
            sW[(tl * 32 + pl) * 4 + t] = valid
                ? (((t >> 1) ? wy1 : wy0) * ((t & 1) ? wx1 : wx0) * mk) : 0.0f;
        }
    }
    __syncthreads();

    // phase B: gather + combine + store (barrier-free, fully line-coalesced)
    const int pl = tid >> 3, cg = tid & 7;
    const int pg = blockIdx.x * 32 + pl;
    __bf16* vout = V + (size_t)pg * KG + cg * 8;

#pragma unroll
    for (int tl = 0; tl < 3; ++tl) {
        const int tap = tapbase + tl;
        const int pbase = (tl * 32 + pl) * 4;
        const int b0 = sB[pbase + 0] + cg * 8, b1 = sB[pbase + 1] + cg * 8;
        const int b2 = sB[pbase + 2] + cg * 8, b3 = sB[pbase + 3] + cg * 8;
        const float w0 = sW[pbase + 0], w1 = sW[pbase + 1];
        const float w2 = sW[pbase + 2], w3 = sW[pbase + 3];
#pragma unroll
        for (int u = 0; u < 4; ++u) {
            const v8bf g0 = *(const v8bf*)(xb + b0 + u * 64);
            const v8bf g1 = *(const v8bf*)(xb + b1 + u * 64);
            const v8bf g2 = *(const v8bf*)(xb + b2 + u * 64);
            const v8bf g3 = *(const v8bf*)(xb + b3 + u * 64);
            v8bf r;
#pragma unroll
            for (int j = 0; j < 8; ++j)
                r[j] = (__bf16)(w0 * (float)g0[j] + w1 * (float)g1[j]
                              + w2 * (float)g2[j] + w3 * (float)g3[j]);
            *(v8bf*)(vout + tap * 256 + u * 64) = r;
        }
    }
}

// ---------- phase 2: dense bf16 MFMA GEMM  out[o][pix] = sum_k V[pix][k]*Bp[o][k]
// (unchanged from R6 -- will read its counters next round before touching it)
__global__ __launch_bounds__(512, 4) void gemm_v(
    const __bf16* __restrict__ V,      // [MTOT][KG]
    const __bf16* __restrict__ bp,     // [COUT][KG]
    const float*  __restrict__ bias,
    float*        __restrict__ out)    // (N,256,56,56)
{
    __shared__ __align__(16) char smem[40960];     // A 8KB | B 32KB ; epi aliases
    __bf16* As = (__bf16*)smem;                    // [64][64]  (row=128B, 8 chunks)
    __bf16* Bs = (__bf16*)(smem + 8192);           // [256][64]

    const int tid  = threadIdx.x;
    const int lane = tid & 63, wv = tid >> 6;      // 8 waves
    const int wm = wv & 1, wn = wv >> 1;           // m-half 32, n-quarter 64
    const int m0 = blockIdx.x * 64;
    const int l15 = lane & 15, q = lane >> 4;

    v4f acc[2][4];
#pragma unroll
    for (int i = 0; i < 2; ++i)
#pragma unroll
        for (int j = 0; j < 4; ++j) acc[i][j] = (v4f)0.f;

    const int arow = (wv << 3) + (lane >> 3);
    const int alc  = (lane & 7) ^ (arow & 7);
    const __bf16* agp = V + (size_t)(m0 + arow) * KG + alc * 8;
    char* alds = smem + (wv << 10);

#pragma unroll 1
    for (int k0 = 0; k0 < KG; k0 += 64) {
        __syncthreads();
        async_copy16(agp + k0, alds);
#pragma unroll
        for (int t = 0; t < 4; ++t) {
            const int brow = t * 64 + (wv << 3) + (lane >> 3);
            const int blc  = (lane & 7) ^ (brow & 7);
            async_copy16(bp + (size_t)brow * KG + k0 + blc * 8,
                         smem + 8192 + ((t * 8 + wv) << 10));
        }
        __syncthreads();

#pragma unroll
        for (int kf = 0; kf < 2; ++kf) {
            v8bf afr[2], bfr[4];
#pragma unroll
            for (int mt = 0; mt < 2; ++mt) {
                const int row = wm * 32 + mt * 16 + l15;
                const int pch = (kf * 4 + q) ^ (row & 7);
                afr[mt] = *(const v8bf*)(As + row * 64 + pch * 8);
            }
#pragma unroll
            for (int nt = 0; nt < 4; ++nt) {
                const int row = wn * 64 + nt * 16 + l15;
                const int pch = (kf * 4 + q) ^ (row & 7);
                bfr[nt] = *(const v8bf*)(Bs + row * 64 + pch * 8);
            }
#pragma unroll
            for (int mt = 0; mt < 2; ++mt)
#pragma unroll
                for (int nt = 0; nt < 4; ++nt)
                    acc[mt][nt] = __builtin_amdgcn_mfma_f32_16x16x32_bf16(
                        afr[mt], bfr[nt], acc[mt][nt], 0, 0, 0);
        }
    }

    __syncthreads();
    float* epi = (float*)(smem + wv * 2176);
    const int pixbase = m0 + wm * 32;
    const int n_img = pixbase / SPIX;
    const int s_base = pixbase - n_img * SPIX;
    float* outb = out + (size_t)n_img * COUT * SPIX + s_base;

#pragma unroll
    for (int nt = 0; nt < 4; ++nt) {
        const float bv = bias[wn * 64 + nt * 16 + l15];
#pragma unroll
        for (int mt = 0; mt < 2; ++mt)
#pragma unroll
            for (int r = 0; r < 4; ++r)
                epi[(mt * 16 + q * 4 + r) * 17 + l15] = acc[mt][nt][r] + bv;
        __syncthreads();
        const int m = lane & 31, oh = lane >> 5;
#pragma unroll
        for (int oc = 0; oc < 8; ++oc) {
            const float v = epi[m * 17 + oc * 2 + oh];
            const int o = wn * 64 + nt * 16 + oc * 2 + oh;
            outb[(size_t)o * SPIX + m] = v;
        }
        __syncthreads();
    }
}

// ---------- R4-verified fused kernel (fallback when ws can't hold V)
__global__ __launch_bounds__(256, 3) void mdcn_fused(
    const __bf16* __restrict__ xb, const float* __restrict__ offs,
    const float* __restrict__ msk, const __bf16* __restrict__ bp,
    const float* __restrict__ bias, float* __restrict__ out)
{
    __shared__ __align__(16) char smem[24576];
    __bf16* A0 = (__bf16*)smem;
    __bf16* A1 = (__bf16*)(smem + 10240);
    int*    sBase = (int*)(smem + 20480);
    float*  sWgt  = (float*)(smem + 22528);
    const int tid  = threadIdx.x;
    const int lane = tid & 63, wv = tid >> 6;
    const int wm = wv & 1, wn = wv >> 1;
    const int m0 = blockIdx.x * 128, o0 = blockIdx.y * 128;
    const int kz = blockIdx.z;
    const int tap_lo = kz ? 5 : 0, tap_hi = kz ? 9 : 5;
    const int l15 = lane & 15, q = lane >> 4;
    const int prow = tid >> 2, pcg = tid & 3;
    v4f acc[4][4];
#pragma unroll
    for (int i = 0; i < 4; ++i)
#pragma unroll
        for (int j = 0; j < 4; ++j) acc[i][j] = (v4f)0.f;
    for (int tap = tap_lo; tap < tap_hi; ++tap) {
        if (tid < 128) {
            const int pg = m0 + tid;
            const int n  = pg / SPIX;
            const int s  = pg - n * SPIX;
            const int h  = s / W_;
            const int w  = s - h * W_;
            const int kY = tap / 3, kX = tap - kY * 3;
            const float dy = offs[n * (18 * SPIX) + (2 * tap) * SPIX + s];
            const float dx = offs[n * (18 * SPIX) + (2 * tap + 1) * SPIX + s];
            const float mk = msk[n * (9 * SPIX) + tap * SPIX + s];
            const float py = dy + (float)(kY + h - 1);
            const float px = dx + (float)(kX + w - 1);
            const float fy0 = floorf(py), fx0 = floorf(px);
            const int y0 = (int)fy0, x0 = (int)fx0;
            const float wy1 = py - fy0, wx1 = px - fx0;
            const float wy0 = 1.0f - wy1, wx0 = 1.0f - wx1;
#pragma unroll
            for (int t = 0; t < 4; ++t) {
                const int yi = y0 + (t >> 1), xi = x0 + (t & 1);
                const bool valid = (yi >= 0) & (yi < H_) & (xi >= 0) & (xi < W_);
                const int yc = min(max(yi, 0), H_ - 1);
                const int xc = min(max(xi, 0), W_ - 1);
                sBase[t * 128 + tid] = (n * SPIX + yc * W_ + xc) * CIN;
                sWgt [t * 128 + tid] = valid
                    ? (((t >> 1) ? wy1 : wy0) * ((t & 1) ? wx1 : wx0) * mk) : 0.0f;
            }
        }
        __syncthreads();
        int   cb0[4], cb1[4];
        float cw0[4], cw1[4];
#pragma unroll
        for (int t = 0; t < 4; ++t) {
            cb0[t] = sBase[t * 128 + prow];
            cw0[t] = sWgt [t * 128 + prow];
            cb1[t] = sBase[t * 128 + prow + 64];
            cw1[t] = sWgt [t * 128 + prow + 64];
        }
        v8bf rv[8];
        {
            const int cch = pcg * 8;
#pragma unroll
            for (int t = 0; t < 4; ++t) {
                rv[t]     = *(const v8bf*)(xb + cb0[t] + cch);
                rv[4 + t] = *(const v8bf*)(xb + cb1[t] + cch);
            }
        }
#pragma unroll
        for (int c8 = 0; c8 < 8; ++c8) {
            const int kk = tap * 8 + c8;
            __bf16* Ab = (kk & 1) ? A1 : A0;
            v8bf r0, r1;
#pragma unroll
            for (int j = 0; j < 8; ++j) {
                r0[j] = (__bf16)(cw0[0] * (float)rv[0][j] + cw0[1] * (float)rv[1][j]
                               + cw0[2] * (float)rv[2][j] + cw0[3] * (float)rv[3][j]);
                r1[j] = (__bf16)(cw1[0] * (float)rv[4][j] + cw1[1] * (float)rv[5][j]
                               + cw1[2] * (float)rv[6][j] + cw1[3] * (float)rv[7][j]);
            }
            *(v8bf*)(Ab + prow * 40 + pcg * 8) = r0;
            *(v8bf*)(Ab + (prow + 64) * 40 + pcg * 8) = r1;
            if (c8 < 7) {
                const int cch = (c8 + 1) * 32 + pcg * 8;
#pragma unroll
                for (int t = 0; t < 4; ++t) {
                    rv[t]     = *(const v8bf*)(xb + cb0[t] + cch);
                    rv[4 + t] = *(const v8bf*)(xb + cb1[t] + cch);
                }
            }
            v8bf bfr[4];
#pragma unroll
            for (int nt = 0; nt < 4; ++nt)
                bfr[nt] = *(const v8bf*)(bp
                    + (size_t)(o0 + wn * 64 + nt * 16 + l15) * KG + kk * 32 + q * 8);
            __syncthreads();
            v8bf afr[4];
#pragma unroll
            for (int mt = 0; mt < 4; ++mt)
                afr[mt] = *(const v8bf*)(Ab + (wm * 64 + mt * 16 + l15) * 40 + q * 8);
#pragma unroll
            for (int mt = 0; mt < 4; ++mt)
#pragma unroll
                for (int nt = 0; nt < 4; ++nt)
                    acc[mt][nt] = __builtin_amdgcn_mfma_f32_16x16x32_bf16(
                        afr[mt], bfr[nt], acc[mt][nt], 0, 0, 0);
        }
    }
    __syncthreads();
    float* epi = (float*)smem + wv * (64 * 20);
    const int pg = m0 + wm * 64 + lane;
    const int n_img = pg / SPIX;
    const int s_pix = pg - n_img * SPIX;
    float* outb = out + (size_t)n_img * COUT * SPIX + s_pix;
#pragma unroll
    for (int nt = 0; nt < 4; ++nt) {
        const float bv = (kz == 0) ? bias[o0 + wn * 64 + nt * 16 + l15] : 0.0f;
#pragma unroll
        for (int mt = 0; mt < 4; ++mt)
#pragma unroll
            for (int r = 0; r < 4; ++r)
                epi[(mt * 16 + q * 4 + r) * 20 + l15] = acc[mt][nt][r] + bv;
        __syncthreads();
#pragma unroll
        for (int c4 = 0; c4 < 4; ++c4) {
            v4f vv = *(const v4f*)(epi + lane * 20 + c4 * 4);
            const int ob = o0 + wn * 64 + nt * 16 + c4 * 4;
            atomicAdd(&outb[(size_t)(ob + 0) * SPIX], vv.x);
            atomicAdd(&outb[(size_t)(ob + 1) * SPIX], vv.y);
            atomicAdd(&outb[(size_t)(ob + 2) * SPIX], vv.z);
            atomicAdd(&outb[(size_t)(ob + 3) * SPIX], vv.w);
        }
        __syncthreads();
    }
}

// ---------- fp32 fallback (round-1 verified, no workspace)
#define BM 64
#define BN 64
#define BKF 32
#define AST 68
#define BST 68
#define CST 65
__global__ __launch_bounds__(256) void mdcn_fallback(
    const float* __restrict__ xs, const float* __restrict__ offs,
    const float* __restrict__ msk, const float* __restrict__ wraw,
    const float* __restrict__ bias, float* __restrict__ out)
{
    __shared__ float smem[BKF * AST + BKF * BST];
    __shared__ int   sBase[4][BM];
    __shared__ float sWgt[4][BM];
    float (*At)[AST] = (float (*)[AST])smem;
    float (*Bt)[BST] = (float (*)[BST])(smem + BKF * AST);
    float (*Cs)[CST] = (float (*)[CST])smem;
    const int tid = threadIdx.x;
    const int m0 = blockIdx.x * BM;
    const int o0 = blockIdx.y * BN;
    const int n  = m0 / SPIX;
    const int s0 = m0 - n * SPIX;
    const int tx = tid & 15, ty = tid >> 4;
    float acc[4][4] = {};
    for (int k = 0; k < 9; ++k) {
        if (tid < BM) {
            const int s = s0 + tid;
            const int h = s / W_;
            const int w = s - h * W_;
            const int kY = k / 3, kX = k - kY * 3;
            const float dy = offs[(size_t)n * (18 * SPIX) + (size_t)(2 * k) * SPIX + s];
            const float dx = offs[(size_t)n * (18 * SPIX) + (size_t)(2 * k + 1) * SPIX + s];
            const float mk = msk[(size_t)n * (9 * SPIX) + (size_t)k * SPIX + s];
            const float py = dy + (float)(kY + h - 1);
            const float px = dx + (float)(kX + w - 1);
            const float fy0 = floorf(py), fx0 = floorf(px);
            const int y0 = (int)fy0, x0 = (int)fx0;
            const float wy1 = py - fy0, wx1 = px - fx0;
            const float wy0 = 1.0f - wy1, wx0 = 1.0f - wx1;
#pragma unroll
            for (int t = 0; t < 4; ++t) {
                const int yi = y0 + (t >> 1), xi = x0 + (t & 1);
                const bool valid = (yi >= 0) & (yi < H_) & (xi >= 0) & (xi < W_);
                const int yc = min(max(yi, 0), H_ - 1);
                const int xc = min(max(xi, 0), W_ - 1);
                float wt = ((t >> 1) ? wy1 : wy0) * ((t & 1) ? wx1 : wx0) * mk;
                sBase[t][tid] = n * (CIN * SPIX) + yc * W_ + xc;
                sWgt[t][tid] = valid ? wt : 0.0f;
            }
        }
        __syncthreads();
        for (int c0 = 0; c0 < CIN; c0 += BKF) {
#pragma unroll
            for (int i = 0; i < 8; ++i) {
                int idx = tid + i * 256;
                int row = idx >> 5, cc = idx & 31;
                int ce = (c0 + cc) * SPIX;
                At[cc][row] = sWgt[0][row] * xs[sBase[0][row] + ce]
                            + sWgt[1][row] * xs[sBase[1][row] + ce]
                            + sWgt[2][row] * xs[sBase[2][row] + ce]
                            + sWgt[3][row] * xs[sBase[3][row] + ce];
            }
#pragma unroll
            for (int i = 0; i < 8; ++i) {
                int idx = tid + i * 256;
                int kf = idx >> 6, o = idx & 63;
                Bt[kf][o] = wraw[(size_t)(o0 + o) * KG + (c0 + kf) * 9 + k];
            }
            __syncthreads();
#pragma unroll
            for (int kf = 0; kf < BKF; ++kf) {
                const float4 a = *(const float4*)&At[kf][ty * 4];
                const float4 b = *(const float4*)&Bt[kf][tx * 4];
                acc[0][0] = fmaf(a.x, b.x, acc[0][0]); acc[0][1] = fmaf(a.x, b.y, acc[0][1]);
                acc[0][2] = fmaf(a.x, b.z, acc[0][2]); acc[0][3] = fmaf(a.x, b.w, acc[0][3]);
                acc[1][0] = fmaf(a.y, b.x, acc[1][0]); acc[1][1] = fmaf(a.y, b.y, acc[1][1]);
                acc[1][2] = fmaf(a.y, b.z, acc[1][2]); acc[1][3] = fmaf(a.y, b.w, acc[1][3]);
                acc[2][0] = fmaf(a.z, b.x, acc[2][0]); acc[2][1] = fmaf(a.z, b.y, acc[2][1]);
                acc[2][2] = fmaf(a.z, b.z, acc[2][2]); acc[2][3] = fmaf(a.z, b.w, acc[2][3]);
                acc[3][0] = fmaf(a.w, b.x, acc[3][0]); acc[3][1] = fmaf(a.w, b.y, acc[3][1]);
                acc[3][2] = fmaf(a.w, b.z, acc[3][2]); acc[3][3] = fmaf(a.w, b.w, acc[3][3]);
            }
            __syncthreads();
        }
    }
#pragma unroll
    for (int i = 0; i < 4; ++i)
#pragma unroll
        for (int j = 0; j < 4; ++j)
            Cs[ty * 4 + i][tx * 4 + j] = acc[i][j] + bias[o0 + tx * 4 + j];
    __syncthreads();
    const int pix = tid & 63, ob = tid >> 6;
    float* outp = out + (size_t)n * COUT * SPIX + s0 + pix;
#pragma unroll
    for (int r = 0; r < 16; ++r) {
        int o = r * 4 + ob;
        outp[(size_t)(o0 + o) * SPIX] = Cs[pix][o];
    }
}

extern "C" void kernel_launch(void* const* d_in, const int* in_sizes, int n_in,
                              void* d_out, int out_size, void* d_ws, size_t ws_size,
                              hipStream_t stream) {
    const float* x    = (const float*)d_in[0];
    const float* offs = (const float*)d_in[1];
    const float* msk  = (const float*)d_in[2];
    const float* w    = (const float*)d_in[3];
    const float* bias = (const float*)d_in[4];
    float* out = (float*)d_out;

    const size_t xb_bytes = (size_t)NB * SPIX * CIN * sizeof(__bf16);    // 12.85 MB
    const size_t bp_bytes = (size_t)KG * COUT * sizeof(__bf16);          // 1.18 MB
    const size_t v_bytes  = (size_t)MTOT * KG * sizeof(__bf16);          // 115.6 MB

    if (ws_size >= xb_bytes + bp_bytes + v_bytes) {
        __bf16* xb = (__bf16*)d_ws;
        __bf16* bp = (__bf16*)((char*)d_ws + xb_bytes);
        __bf16* V  = (__bf16*)((char*)d_ws + xb_bytes + bp_bytes);
        prep_x<<<dim3(49, 4, 8), 256, 0, stream>>>(x, xb);
        prep_w<<<dim3((COUT * KG + 255) / 256), 256, 0, stream>>>(w, bp);
        im2col_v<<<dim3(MTOT / 32, 3), 256, 0, stream>>>(xb, offs, msk, V);
        gemm_v<<<dim3(MTOT / 64), 512, 0, stream>>>(V, bp, bias, out);
    } else if (ws_size >= xb_bytes + bp_bytes) {
        __bf16* xb = (__bf16*)d_ws;
        __bf16* bp = (__bf16*)((char*)d_ws + xb_bytes);
        prep_x<<<dim3(49, 4, 8), 256, 0, stream>>>(x, xb);
        prep_w<<<dim3((COUT * KG + 255) / 256), 256, 0, stream>>>(w, bp);
        hipMemsetAsync(out, 0, (size_t)out_size * sizeof(float), stream);
        mdcn_fused<<<dim3(MTOT / 128, COUT / 128, 2), 256, 0, stream>>>(
            xb, offs, msk, bp, bias, out);
    } else {
        mdcn_fallback<<<dim3(MTOT / BM, COUT / BN), 256, 0, stream>>>(
            x, offs, msk, w, bias, out);
    }
}